// Round 11
// baseline (283.463 us; speedup 1.0000x reference)
//
#include <hip/hip_runtime.h>
#include <hip/hip_bf16.h>
#include <stdint.h>

// GINE edge layer on MI355X:
//   de = concat([e, x[src], x[dst]]) @ W1 + b1 ; de = silu(de); h = e + de
//   out = GraphNorm(h, seg=batch[src])  (per-graph mean/var, ms-scaled mean)
// Decomposition: concat@W1 = e@W1a + xb[src] + xc[dst], xb/xc per NODE.
// GraphNorm one-pass: var = E[h^2] - m^2*ms*(2-ms); out = A[g,d]*h + C[g,d].
// R2/R3: LDS fp-atomic RMW serializes -> MFMA one-hot segsum.
// R5/R6: e re-read killed; gather chain vectorized (bf16 xbc + b1 fold).
// R7-R10: occupancy/pipelining sweeps -> edgegemm converged ~99us (stall-dominated
//   phase structure); remaining lever = eliminate work, not reschedule it.
// R11: FUSE segment sums into persistent edgegemm (h is already in registers at
//   combine). Per tile: h -> subtiled-transposed LDS (et reuse, b128+XOR) ->
//   per-wave one-hot MFMA accumulate S/Q (32 d/wave, 80 VGPR) + counts via
//   ones-B MFMA (wave 0). One-hot from batch[srcI[r]] (input-only, no coherence
//   hazard). k_sums dispatch + its 82 MB h re-read ELIMINATED.

typedef float   f32x4 __attribute__((ext_vector_type(4)));
typedef short   s16x8 __attribute__((ext_vector_type(8)));
typedef uint32_t u32x4 __attribute__((ext_vector_type(4)));

#define NGRAPH 64
#define PSTRIDE (NGRAPH * 256 * 2 + NGRAPH)   // floats per block-partial: sum|sq|cnt

__device__ __forceinline__ void gld16(const void* g, void* l) {
  __builtin_amdgcn_global_load_lds(
      (const __attribute__((address_space(1))) uint32_t*)g,
      (__attribute__((address_space(3))) uint32_t*)l, 16, 0, 0);
}

// native LDS f32 add, no return (fallback path only)
__device__ __forceinline__ void ds_addf(float* p, float v) {
  asm volatile("ds_add_f32 %0, %1"
               :: "v"((__attribute__((address_space(3))) float*)p), "v"(v));
}

__device__ __forceinline__ short f2bf(float f) {
  __bf16 b = (__bf16)f;                       // RTNE
  return __builtin_bit_cast(short, b);
}
__device__ __forceinline__ float bf2f(uint32_t u) {
  return __uint_as_float((u & 0xffffu) << 16);
}

// legacy-path permuted d-index (atomic fallback kernel only)
__device__ __forceinline__ int dperm(int d) { return (d >> 3) | ((d & 7) << 5); }

// ---------------------------------------------------------------- zero tables
__global__ __launch_bounds__(256) void k_zero(float* p, int n) {
  int i = blockIdx.x * 256 + threadIdx.x;
  if (i < n) p[i] = 0.f;
}

// ------------------------------------------- W1 f32 [768][256] -> transposed bf16
__global__ __launch_bounds__(256) void k_wconv(const float* __restrict__ W1,
                                               uint16_t* __restrict__ wta,
                                               uint16_t* __restrict__ wtbc) {
  int k = blockIdx.x;            // 0..767
  int n = threadIdx.x;           // 0..255
  uint16_t v = (uint16_t)f2bf(W1[k * 256 + n]);
  if (k < 256)      wta[n * 256 + k] = v;
  else if (k < 512) wtbc[n * 256 + (k - 256)] = v;
  else              wtbc[(n + 256) * 256 + (k - 512)] = v;
}

// ------------------------------------------------- node GEMM: xbc = x @ Wbc (bf16 out)
// xbc[node][0..256) = x@W1b ; xbc[node][256..512) = x@W1c + b1  (b1 folded)
__global__ __launch_bounds__(256, 2) void k_nodegemm(const float* __restrict__ x,
                                                     const uint16_t* __restrict__ wtbc,
                                                     const float* __restrict__ b1,
                                                     uint16_t* __restrict__ xbc, int NV) {
  __shared__ float    xt[32 * 64];
  __shared__ uint16_t wtb[512 * 64];
  const int tid = threadIdx.x, wave = tid >> 6, lane = tid & 63;
  const int m0 = blockIdx.x * 32;
  const int cl = lane & 15, rq = lane >> 4;

  f32x4 acc[2][8];
#pragma unroll
  for (int a = 0; a < 2; ++a)
#pragma unroll
    for (int b = 0; b < 8; ++b) acc[a][b] = (f32x4)0.f;

  for (int kk = 0; kk < 4; ++kk) {
    const int k0 = kk * 64;
#pragma unroll
    for (int ii = 0; ii < 2; ++ii) {
      int i = wave * 2 + ii;
      int row = i * 4 + rq;
      int k8 = cl ^ (row & 15);
      int grow = m0 + row; if (grow > NV - 1) grow = NV - 1;
      gld16((const char*)x + ((size_t)grow * 256 + k0) * 4 + k8 * 16,
            (char*)xt + i * 1024);
    }
#pragma unroll
    for (int ii = 0; ii < 16; ++ii) {
      int i = wave * 16 + ii;
      int n = i * 8 + (lane >> 3);
      int k8 = (lane & 7) ^ (n & 7);
      gld16((const char*)wtbc + ((size_t)n * 256 + k0) * 2 + k8 * 16,
            (char*)wtb + i * 1024);
    }
    __syncthreads();
#pragma unroll
    for (int ks = 0; ks < 2; ++ks) {
      s16x8 a[2], b[8];
#pragma unroll
      for (int mt = 0; mt < 2; ++mt) {
        int row = mt * 16 + cl;
        int sbase = ks * 8 + rq * 2;
        int sw = (row & 15) << 4;
        f32x4 f0 = *(const f32x4*)((const char*)xt + row * 256 + (((sbase    ) << 4) ^ sw));
        f32x4 f1 = *(const f32x4*)((const char*)xt + row * 256 + (((sbase + 1) << 4) ^ sw));
        s16x8 t;
        t[0] = f2bf(f0[0]); t[1] = f2bf(f0[1]); t[2] = f2bf(f0[2]); t[3] = f2bf(f0[3]);
        t[4] = f2bf(f1[0]); t[5] = f2bf(f1[1]); t[6] = f2bf(f1[2]); t[7] = f2bf(f1[3]);
        a[mt] = t;
      }
#pragma unroll
      for (int nt = 0; nt < 8; ++nt) {
        int n = wave * 128 + nt * 16 + cl;
        int byt = n * 128 + ((((ks * 4 + rq)) << 4) ^ ((n & 7) << 4));
        b[nt] = *(const s16x8*)((const char*)wtb + byt);
      }
#pragma unroll
      for (int mt = 0; mt < 2; ++mt)
#pragma unroll
        for (int nt = 0; nt < 8; ++nt)
          acc[mt][nt] = __builtin_amdgcn_mfma_f32_16x16x32_bf16(a[mt], b[nt], acc[mt][nt], 0, 0, 0);
    }
    __syncthreads();
  }
  float b1v[8];
#pragma unroll
  for (int nt = 0; nt < 8; ++nt) {
    int col = wave * 128 + nt * 16 + cl;
    b1v[nt] = (col >= 256) ? b1[col - 256] : 0.f;
  }
#pragma unroll
  for (int mt = 0; mt < 2; ++mt)
#pragma unroll
    for (int q = 0; q < 4; ++q) {
      int row = m0 + mt * 16 + rq * 4 + q;
      if (row < NV) {
#pragma unroll
        for (int nt = 0; nt < 8; ++nt) {
          int col = wave * 128 + nt * 16 + cl;
          xbc[(size_t)row * 512 + col] = (uint16_t)f2bf(acc[mt][nt][q] + b1v[nt]);
        }
      }
    }
}

// ------------------------------------------------- edge GEMM + epilogue + SUMS
// grid<=256 persistent, 512 thr = 8 waves (2 row-grp x 4 col-grp), grid-stride
// over 64-row tiles. W1a^T RESIDENT in LDS 128 KB: byte = n*512 + ((k8^(n&7))<<4).
// et 32 KB, triple-duty per tile: e-tile (chunk-major) -> acc relayout -> h-transposed.
// h-transposed subtiled layout (for sums B-frags):
//   byte(r,d) = (d>>4)*2048 + (r>>2)*128 + (((r&3)*32 + (d&15)*2) ^ (((r>>2)&3)<<5))
// Sums: per-wave one-hot MFMA, wave w owns d in [w*32,w*32+32); counts via
// ones-B MFMA on wave 0. One-hot P from batch[srcI[r]] (pure-input reads).
template <bool BF16H>
__global__ __launch_bounds__(512, 1) void k_edgegemm(
    const float* __restrict__ e, const uint16_t* __restrict__ wta,
    const uint16_t* __restrict__ xbc,
    const int* __restrict__ srcI, const int* __restrict__ dstI,
    const int* __restrict__ batch, void* __restrict__ hout,
    int* __restrict__ seg, float* __restrict__ part, int E, int ntiles) {
  __shared__ alignas(16) uint16_t wl[256 * 256];  // 128 KB resident W1a^T
  __shared__ alignas(16) uint16_t et[64 * 256];   // 32 KB multi-purpose
  const int tid = threadIdx.x, wave = tid >> 6, lane = tid & 63;
  const int wr = wave >> 2, wc = wave & 3;
  const int cl = lane & 15, rq = lane >> 4;
  const int rr = tid >> 3;                 // 0..63 (row in tile)
  const int cb = tid & 7;                  // chunk base

  // ---- stage resident W once ----
#pragma unroll
  for (int i = 0; i < 16; ++i) {
    int n = i * 16 + (tid >> 5);
    int k8 = (tid & 31) ^ (n & 7);
    gld16((const char*)wta + ((size_t)n * 256 + k8 * 8) * 2,
          (char*)wl + i * 8192 + tid * 16);
  }

  // sums accumulators: wave owns d in [wave*32, wave*32+32)
  f32x4 accS[4][2], accQ[4][2], accC[4];
#pragma unroll
  for (int gt = 0; gt < 4; ++gt) {
    accC[gt] = (f32x4)0.f;
#pragma unroll
    for (int dt = 0; dt < 2; ++dt) { accS[gt][dt] = (f32x4)0.f; accQ[gt][dt] = (f32x4)0.f; }
  }

  f32x4 er[8];                             // e prefetch: 4 chunks x 2 f32x4
  auto loadE = [&](int t) {
    int r = t * 64 + rr; int rc = r < E ? r : E - 1;
    const float* ep = e + (size_t)rc * 256;
#pragma unroll
    for (int i = 0; i < 4; ++i) {
      int s = cb + 8 * i;
      er[2 * i]     = *(const f32x4*)(ep + s * 8);
      er[2 * i + 1] = *(const f32x4*)(ep + s * 8 + 4);
    }
  };
  auto writeE = [&]() {
#pragma unroll
    for (int i = 0; i < 4; ++i) {
      int s = cb + 8 * i;
      f32x4 f0 = er[2 * i], f1 = er[2 * i + 1];
      s16x8 t;
      t[0] = f2bf(f0[0]); t[1] = f2bf(f0[1]); t[2] = f2bf(f0[2]); t[3] = f2bf(f0[3]);
      t[4] = f2bf(f1[0]); t[5] = f2bf(f1[1]); t[6] = f2bf(f1[2]); t[7] = f2bf(f1[3]);
      *(s16x8*)((char*)et + s * 1024 + ((rr * 16) ^ ((s & 3) << 4))) = t;
    }
  };

  int t = blockIdx.x;
  const int G = gridDim.x;
  if (t < ntiles) { loadE(t); writeE(); }
  __syncthreads();                          // W staged + e(tile0) visible

  for (; t < ntiles; t += G) {
    const int tn = t + G;
    const int rt = t * 64;
    // idx for current tile (per-thread row rr)
    int r = rt + rr;
    bool valid = r < E;
    int rc = valid ? r : E - 1;
    int sA = srcI[rc], dA = dstI[rc];
    int gseg = batch[sA];
    if (tn < ntiles) loadE(tn);             // prefetch next e (hidden under K-loop)

    // ---- barrier-free K-loop over resident W ----
    f32x4 acc[2][4];
#pragma unroll
    for (int a = 0; a < 2; ++a)
#pragma unroll
      for (int b = 0; b < 4; ++b) acc[a][b] = (f32x4)0.f;
#pragma unroll
    for (int kk = 0; kk < 8; ++kk) {
      s16x8 a[2], b[4];
#pragma unroll
      for (int mt = 0; mt < 2; ++mt) {
        int row = wr * 32 + mt * 16 + cl;
        int c8s = kk * 4 + rq;
        a[mt] = *(const s16x8*)((const char*)et + c8s * 1024 + ((row * 16) ^ (rq << 4)));
      }
#pragma unroll
      for (int nt = 0; nt < 4; ++nt) {
        int n = wc * 64 + nt * 16 + cl;
        int kc = kk * 4 + rq;
        b[nt] = *(const s16x8*)((const char*)wl + n * 512 + ((kc ^ (n & 7)) << 4));
      }
#pragma unroll
      for (int mt = 0; mt < 2; ++mt)
#pragma unroll
        for (int nt = 0; nt < 4; ++nt)
          acc[mt][nt] = __builtin_amdgcn_mfma_f32_16x16x32_bf16(a[mt], b[nt], acc[mt][nt], 0, 0, 0);
    }

    // ---- gathers for current tile (L3; consumed 2 barriers later) ----
    u32x4 gb[4], gc[4];
#pragma unroll
    for (int i = 0; i < 4; ++i) {
      int c8 = cb + 8 * i;
      gb[i] = *(const u32x4*)(xbc + (size_t)sA * 512 + c8 * 8);
      gc[i] = *(const u32x4*)(xbc + (size_t)dA * 512 + 256 + c8 * 8);
    }
    // ---- one-hot seg values for sums: lane (cl,rq) needs rows ks*32+rq*8+j ----
    int gsg[16];
    if (part) {
#pragma unroll
      for (int k2 = 0; k2 < 16; ++k2) {
        int rs = rt + (k2 >> 3) * 32 + rq * 8 + (k2 & 7);
        gsg[k2] = (rs < E) ? batch[srcI[rs]] : -1;   // -1: matches no graph
      }
    }
    // ---- e residual out of et before relayout clobbers it ----
    s16x8 ev[4];
#pragma unroll
    for (int i = 0; i < 4; ++i) {
      int c8 = cb + 8 * i;
      ev[i] = *(const s16x8*)((const char*)et + c8 * 1024 + ((rr * 16) ^ ((c8 & 3) << 4)));
    }
    __syncthreads();                        // A: all e-reads of et done

    // ---- relayout acc -> et (bf16, chunk-major) ----
#pragma unroll
    for (int mt = 0; mt < 2; ++mt)
#pragma unroll
      for (int nt = 0; nt < 4; ++nt) {
        int col = wc * 64 + nt * 16 + cl;
        int c8 = col >> 3;
        char* base = (char*)et + c8 * 1024 + (col & 7) * 2;
#pragma unroll
        for (int q = 0; q < 4; ++q) {
          int row = wr * 32 + mt * 16 + rq * 4 + q;
          *(uint16_t*)(base + ((row * 16) ^ ((c8 & 3) << 4))) =
              (uint16_t)f2bf(acc[mt][nt][q]);
        }
      }
    __syncthreads();                        // B: relayout visible

    // ---- combine + store h; keep bf16 h in regs for the sums transpose ----
    if (cb == 0 && valid) seg[r] = gseg;
    s16x8 hov[4];
#pragma unroll
    for (int i = 0; i < 4; ++i) {
      int c8 = cb + 8 * i;
      int sw = (c8 & 3) << 4;
      s16x8 av = *(const s16x8*)((const char*)et + c8 * 1024 + ((rr * 16) ^ sw));
      f32x4 f0, f1;
#pragma unroll
      for (int j = 0; j < 8; ++j) {
        uint32_t xbw = ((const uint32_t*)&gb[i])[j >> 1];
        uint32_t xcw = ((const uint32_t*)&gc[i])[j >> 1];
        float xbf = bf2f((j & 1) ? (xbw >> 16) : xbw);
        float xcf = bf2f((j & 1) ? (xcw >> 16) : xcw);
        float de = bf2f((uint16_t)av[j]) + xbf + xcf;      // b1 folded in xc
        float sig = 1.f / (1.f + __expf(-de));
        float h = bf2f((uint16_t)ev[i][j]) + de * sig;
        hov[i][j] = f2bf(h);
        if (!BF16H) { if (j < 4) f0[j] = h; else f1[j - 4] = h; }
      }
      if (valid) {
        if (BF16H) {
          *(s16x8*)((uint16_t*)hout + (size_t)r * 256 + c8 * 8) = hov[i];
        } else {
          float* hp_ = (float*)hout + (size_t)r * 256 + c8 * 8;
          *(f32x4*)hp_ = f0; *(f32x4*)(hp_ + 4) = f1;
        }
      }
    }
    __syncthreads();                        // C: et combine-reads done

    // ---- h -> et in subtiled-transposed layout (b128, XOR-swizzled) ----
    if (part) {
#pragma unroll
      for (int i = 0; i < 4; ++i) {
        int c8 = cb + 8 * i;
        int wb = (c8 >> 1) * 2048 + (rr >> 2) * 128
               + ((((rr & 3) * 32) + ((c8 & 1) * 16)) ^ (((rr >> 2) & 3) << 5));
        *(s16x8*)((char*)et + wb) = hov[i];  // invalid rows harmless: one-hot=0
      }
    }
    __syncthreads();                        // D: h-transposed visible

    // ---- sums: per-wave one-hot MFMA over the 64 rows ----
    if (part) {
#pragma unroll
      for (int ks = 0; ks < 2; ++ks) {
        s16x8 afk[4];
#pragma unroll
        for (int gt = 0; gt < 4; ++gt) {
          int gcol = gt * 16 + cl;
          u32x4 aw;
#pragma unroll
          for (int jp = 0; jp < 4; ++jp)
            aw[jp] = (gsg[ks * 8 + 2 * jp]     == gcol ? 0x3F80u     : 0u)
                   | (gsg[ks * 8 + 2 * jp + 1] == gcol ? 0x3F800000u : 0u);
          afk[gt] = __builtin_bit_cast(s16x8, aw);
        }
#pragma unroll
        for (int dt = 0; dt < 2; ++dt) {
          s16x8 bf;
#pragma unroll
          for (int j = 0; j < 8; ++j) {
            int rsub = ks * 8 + rq * 2 + (j >> 2);
            int rb = (wave * 2 + dt) * 2048 + rsub * 128
                   + ((((j & 3) * 32) + cl * 2) ^ ((rsub & 3) << 5));
            bf[j] = *(const short*)((const char*)et + rb);
          }
          s16x8 qf;
#pragma unroll
          for (int j = 0; j < 8; ++j) {
            float f = bf2f((uint16_t)bf[j]);
            qf[j] = f2bf(f * f);
          }
#pragma unroll
          for (int gt = 0; gt < 4; ++gt) {
            accS[gt][dt] = __builtin_amdgcn_mfma_f32_16x16x32_bf16(afk[gt], bf, accS[gt][dt], 0, 0, 0);
            accQ[gt][dt] = __builtin_amdgcn_mfma_f32_16x16x32_bf16(afk[gt], qf, accQ[gt][dt], 0, 0, 0);
          }
        }
        if (wave == 0) {                    // counts: B = ones
          s16x8 ones;
#pragma unroll
          for (int j = 0; j < 8; ++j) ones[j] = (short)0x3F80;
#pragma unroll
          for (int gt = 0; gt < 4; ++gt)
            accC[gt] = __builtin_amdgcn_mfma_f32_16x16x32_bf16(afk[gt], ones, accC[gt], 0, 0, 0);
        }
      }
    }
    __syncthreads();                        // E: et sums-reads done

    if (tn < ntiles) writeE();              // stage e for next tile
    __syncthreads();                        // F: next e visible
  }

  // ---- write per-block sum partials ----
  if (part) {
    float* pb = part + (size_t)blockIdx.x * PSTRIDE;
#pragma unroll
    for (int gt = 0; gt < 4; ++gt)
#pragma unroll
      for (int dt = 0; dt < 2; ++dt)
#pragma unroll
        for (int q = 0; q < 4; ++q) {
          int g = gt * 16 + rq * 4 + q;     // C-frag: row=(lane>>4)*4+reg
          int d = wave * 32 + dt * 16 + cl; //         col=lane&15
          pb[g * 256 + d] = accS[gt][dt][q];
          pb[NGRAPH * 256 + g * 256 + d] = accQ[gt][dt][q];
        }
    if (wave == 0 && cl == 0) {
#pragma unroll
      for (int gt = 0; gt < 4; ++gt)
#pragma unroll
        for (int q = 0; q < 4; ++q)
          pb[NGRAPH * 256 * 2 + gt * 16 + rq * 4 + q] = accC[gt][q];
    }
  }
}

// ------------------------------------------------- legacy atomic k_sums (fallback)
__global__ __launch_bounds__(512, 1) void k_sums_atomic(const float* __restrict__ h,
                                                        const int* __restrict__ seg,
                                                        float* __restrict__ gsum,
                                                        float* __restrict__ gsq,
                                                        float* __restrict__ gcnt, int E) {
  __shared__ float ls[NGRAPH * 256];      // d-permuted layout
  __shared__ float lq[NGRAPH * 256];
  __shared__ float lc[NGRAPH];
  const int t = threadIdx.x;
  for (int i = t; i < NGRAPH * 256; i += 512) { ls[i] = 0.f; lq[i] = 0.f; }
  if (t < NGRAPH) lc[t] = 0.f;
  __syncthreads();
  const int ro = t >> 5, c = t & 31;
  const int step = gridDim.x * 16;
  for (int r0 = blockIdx.x * 16; r0 < E; r0 += step) {
    int r = r0 + ro;
    if (r < E) {
      int g = seg[r];
      const float* hp = h + (size_t)r * 256 + c * 8;
      if (c == 0) ds_addf(&lc[g], 1.f);
      float* bs = ls + g * 256;
      float* bq = lq + g * 256;
#pragma unroll
      for (int j = 0; j < 8; ++j) {
        int dp = c | (j << 5);
        float v = hp[j];
        ds_addf(&bs[dp], v);
        ds_addf(&bq[dp], v * v);
      }
    }
  }
  asm volatile("s_waitcnt lgkmcnt(0)" ::: "memory");
  __syncthreads();
  for (int i = t; i < NGRAPH * 256; i += 512) {
    unsafeAtomicAdd(&gsum[i], ls[i]);
    unsafeAtomicAdd(&gsq[i], lq[i]);
  }
  if (t < NGRAPH) unsafeAtomicAdd(&gcnt[t], lc[t]);
}

// ------------------------------------------------- per-(g,d) affine tables
// NB>0: reduce NB block-partials (natural layout); NB==0: legacy dperm'd tables
__global__ __launch_bounds__(256) void k_stats(const float* __restrict__ part, int NB,
                                               const float* __restrict__ gsum,
                                               const float* __restrict__ gsq,
                                               const float* __restrict__ gcnt,
                                               const float* __restrict__ w,
                                               const float* __restrict__ b,
                                               const float* __restrict__ ms,
                                               float* __restrict__ atab,
                                               float* __restrict__ ctab) {
  int g = blockIdx.x, d = threadIdx.x;
  float s = 0.f, q = 0.f, cn = 0.f;
  if (NB > 0) {
    const float* ps = part + g * 256 + d;
    const float* pq = part + NGRAPH * 256 + g * 256 + d;
    const float* pc = part + NGRAPH * 256 * 2 + g;
#pragma unroll 4
    for (int bb = 0; bb < NB; ++bb) {
      size_t o = (size_t)bb * PSTRIDE;
      s  += ps[o];
      q  += pq[o];
      cn += pc[o];
    }
  } else {
    int dp = dperm(d);
    s = gsum[g * 256 + dp]; q = gsq[g * 256 + dp]; cn = gcnt[g];
  }
  float cnt = fmaxf(cn, 1.f);
  float m   = s / cnt;
  float msq = q / cnt;
  float sc  = ms[d];
  float var = msq - m * m * sc * (2.f - sc);
  float rstd = rsqrtf(fmaxf(var, 0.f) + 1e-5f);
  float A = w[d] * rstd;
  atab[g * 256 + d] = A;
  ctab[g * 256 + d] = b[d] - A * sc * m;
}

// ------------------------------------------------- apply: out = A[g]*h + C[g]
template <bool BF16H>
__global__ __launch_bounds__(256) void k_apply(const void* __restrict__ h,
                                               const int* __restrict__ seg,
                                               const float* __restrict__ atab,
                                               const float* __restrict__ ctab,
                                               float* __restrict__ out, int E) {
  const long long total = (long long)E * 32;
  for (long long i = (long long)blockIdx.x * 256 + threadIdx.x; i < total;
       i += (long long)gridDim.x * 256) {
    int row = (int)(i >> 5);
    int c8 = ((int)i & 31) * 8;
    int g = seg[row];
    const f32x4* Ap = (const f32x4*)(atab + g * 256 + c8);
    const f32x4* Cp = (const f32x4*)(ctab + g * 256 + c8);
    f32x4 A0 = Ap[0], A1 = Ap[1], C0 = Cp[0], C1 = Cp[1];
    f32x4 h0, h1;
    if (BF16H) {
      u32x4 p = *(const u32x4*)((const uint16_t*)h + (size_t)row * 256 + c8);
      h0[0] = bf2f(p[0]); h0[1] = bf2f(p[0] >> 16);
      h0[2] = bf2f(p[1]); h0[3] = bf2f(p[1] >> 16);
      h1[0] = bf2f(p[2]); h1[1] = bf2f(p[2] >> 16);
      h1[2] = bf2f(p[3]); h1[3] = bf2f(p[3] >> 16);
    } else {
      const f32x4* hp = (const f32x4*)((const float*)h + (size_t)row * 256 + c8);
      h0 = hp[0]; h1 = hp[1];
    }
    f32x4 o0 = A0 * h0 + C0, o1 = A1 * h1 + C1;
    f32x4* op = (f32x4*)(out + (size_t)row * 256 + c8);
    op[0] = o0; op[1] = o1;
  }
}

// ----------------------------------------------------------------- launch
extern "C" void kernel_launch(void* const* d_in, const int* in_sizes, int n_in,
                              void* d_out, int out_size, void* d_ws, size_t ws_size,
                              hipStream_t stream) {
  const float* x     = (const float*)d_in[0];
  const float* e     = (const float*)d_in[1];
  const int*   batch = (const int*)d_in[2];
  const int*   eidx  = (const int*)d_in[3];
  const float* W1    = (const float*)d_in[4];
  const float* b1    = (const float*)d_in[5];
  const float* gw    = (const float*)d_in[6];
  const float* gb    = (const float*)d_in[7];
  const float* gms   = (const float*)d_in[8];
  const int NV = in_sizes[0] / 256;
  const int E  = in_sizes[1] / 256;
  const int* srcI = eidx;
  const int* dstI = eidx + E;

  char* ws = (char*)d_ws;
  size_t off = 0;
  auto alloc = [&](size_t bytes) {
    size_t o = off;
    off += (bytes + 255) & ~(size_t)255;
    return o;
  };
  size_t o_wta  = alloc(256 * 256 * 2);
  size_t o_wtbc = alloc(512 * 256 * 2);
  size_t o_gsum = alloc(NGRAPH * 256 * 4);
  size_t o_gsq  = alloc(NGRAPH * 256 * 4);
  size_t o_gcnt = alloc(256);
  size_t o_atab = alloc(NGRAPH * 256 * 4);
  size_t o_ctab = alloc(NGRAPH * 256 * 4);
  size_t o_seg  = alloc((size_t)E * 4);
  size_t o_xbc  = alloc((size_t)NV * 512 * 2);     // bf16
  size_t o_h    = alloc((size_t)E * 256 * 2);
  const bool fast = ws_size >= off;   // h (bf16) fits in ws? else stage f32 in d_out

  uint16_t* wta  = (uint16_t*)(ws + o_wta);
  uint16_t* wtbc = (uint16_t*)(ws + o_wtbc);
  float* gsum = (float*)(ws + o_gsum);
  float* gsq  = (float*)(ws + o_gsq);
  float* gcnt = (float*)(ws + o_gcnt);
  float* atab = (float*)(ws + o_atab);
  float* ctab = (float*)(ws + o_ctab);
  int*   seg  = (int*)(ws + o_seg);
  uint16_t* xbc = (uint16_t*)(ws + o_xbc);
  void*  hbuf = fast ? (void*)(ws + o_h) : d_out;
  // fast path: block-partials at the START of d_out (<33 MB << 164 MB);
  // written by fused edgegemm, consumed by k_stats, then overwritten by k_apply.
  float* part = fast ? (float*)d_out : nullptr;

  const int ntiles = (E + 63) / 64;
  const int egrid = ntiles < 256 ? ntiles : 256;
  const int NB = fast ? egrid : 0;

  k_wconv<<<768, 256, 0, stream>>>(W1, wta, wtbc);
  k_nodegemm<<<(NV + 31) / 32, 256, 0, stream>>>(x, wtbc, b1, xbc, NV);
  if (fast) {
    k_edgegemm<true><<<egrid, 512, 0, stream>>>(e, wta, xbc, srcI, dstI,
                                                batch, hbuf, seg, part, E, ntiles);
  } else {
    const int nz = NGRAPH * 256 * 2 + 64;   // gsum|gsq|gcnt contiguous
    k_zero<<<(nz + 255) / 256, 256, 0, stream>>>(gsum, nz);
    k_edgegemm<false><<<egrid, 512, 0, stream>>>(e, wta, xbc, srcI, dstI,
                                                 batch, hbuf, seg, nullptr, E, ntiles);
    k_sums_atomic<<<256, 512, 0, stream>>>((const float*)hbuf, seg, gsum, gsq, gcnt, E);
  }
  k_stats<<<NGRAPH, 256, 0, stream>>>(part, NB, gsum, gsq, gcnt, gw, gb, gms, atab, ctab);
  if (fast)
    k_apply<true><<<2048, 256, 0, stream>>>(hbuf, seg, atab, ctab, (float*)d_out, E);
  else
    k_apply<false><<<2048, 256, 0, stream>>>(hbuf, seg, atab, ctab, (float*)d_out, E);
}

// Round 12
// 235.064 us; speedup vs baseline: 1.2059x; 1.2059x over previous
//
#include <hip/hip_runtime.h>
#include <hip/hip_bf16.h>
#include <stdint.h>

// GINE edge layer on MI355X:
//   de = concat([e, x[src], x[dst]]) @ W1 + b1 ; de = silu(de); h = e + de
//   out = GraphNorm(h, seg=batch[src])  (per-graph mean/var, ms-scaled mean)
// Decomposition: concat@W1 = e@W1a + xb[src] + xc[dst], xb/xc per NODE.
// GraphNorm one-pass: var = E[h^2] - m^2*ms*(2-ms); out = A[g,d]*h + C[g,d].
// R2/R3: LDS fp-atomic RMW serializes -> MFMA one-hot segsum.
// R5/R6: e re-read killed; gather chain vectorized (bf16 xbc + b1 fold).
// R7-R10: occupancy/pipelining sweeps -> edgegemm ~99us; lever = eliminate work.
// R11 FAIL: fused sums cost +96us from (a) 32 scattered scalar seg loads/thread,
//   (b) B-frags as 8x ds_read_u16 (layout broke b128 property).
// R12 fused sums CORRECTED: (a) seg via uniform i32x4 srcI loads (broadcast) +
//   batch gathers from L2-resident 40KB table, issued early; (b) h staged in
//   k_sums_mfma's PROVEN d-major layout (granule-XOR (d>>3)&3) -> B-frag is a
//   single ds_read_b128; writes are base+imm ds_write_b16 (4-way, cheap).
//   k_sums dispatch + its 123MB h re-read eliminated.

typedef float   f32x4 __attribute__((ext_vector_type(4)));
typedef short   s16x8 __attribute__((ext_vector_type(8)));
typedef uint32_t u32x4 __attribute__((ext_vector_type(4)));
typedef int     i32x4 __attribute__((ext_vector_type(4)));

#define NGRAPH 64
#define PSTRIDE (NGRAPH * 256 * 2 + NGRAPH)   // floats per block-partial: sum|sq|cnt

__device__ __forceinline__ void gld16(const void* g, void* l) {
  __builtin_amdgcn_global_load_lds(
      (const __attribute__((address_space(1))) uint32_t*)g,
      (__attribute__((address_space(3))) uint32_t*)l, 16, 0, 0);
}

// native LDS f32 add, no return (fallback path only)
__device__ __forceinline__ void ds_addf(float* p, float v) {
  asm volatile("ds_add_f32 %0, %1"
               :: "v"((__attribute__((address_space(3))) float*)p), "v"(v));
}

__device__ __forceinline__ short f2bf(float f) {
  __bf16 b = (__bf16)f;                       // RTNE
  return __builtin_bit_cast(short, b);
}
__device__ __forceinline__ float bf2f(uint32_t u) {
  return __uint_as_float((u & 0xffffu) << 16);
}

// legacy-path permuted d-index (atomic fallback kernel only)
__device__ __forceinline__ int dperm(int d) { return (d >> 3) | ((d & 7) << 5); }

// ---------------------------------------------------------------- zero tables
__global__ __launch_bounds__(256) void k_zero(float* p, int n) {
  int i = blockIdx.x * 256 + threadIdx.x;
  if (i < n) p[i] = 0.f;
}

// ------------------------------------------- W1 f32 [768][256] -> transposed bf16
__global__ __launch_bounds__(256) void k_wconv(const float* __restrict__ W1,
                                               uint16_t* __restrict__ wta,
                                               uint16_t* __restrict__ wtbc) {
  int k = blockIdx.x;            // 0..767
  int n = threadIdx.x;           // 0..255
  uint16_t v = (uint16_t)f2bf(W1[k * 256 + n]);
  if (k < 256)      wta[n * 256 + k] = v;
  else if (k < 512) wtbc[n * 256 + (k - 256)] = v;
  else              wtbc[(n + 256) * 256 + (k - 512)] = v;
}

// ------------------------------------------------- node GEMM: xbc = x @ Wbc (bf16 out)
// xbc[node][0..256) = x@W1b ; xbc[node][256..512) = x@W1c + b1  (b1 folded)
__global__ __launch_bounds__(256, 2) void k_nodegemm(const float* __restrict__ x,
                                                     const uint16_t* __restrict__ wtbc,
                                                     const float* __restrict__ b1,
                                                     uint16_t* __restrict__ xbc, int NV) {
  __shared__ float    xt[32 * 64];
  __shared__ uint16_t wtb[512 * 64];
  const int tid = threadIdx.x, wave = tid >> 6, lane = tid & 63;
  const int m0 = blockIdx.x * 32;
  const int cl = lane & 15, rq = lane >> 4;

  f32x4 acc[2][8];
#pragma unroll
  for (int a = 0; a < 2; ++a)
#pragma unroll
    for (int b = 0; b < 8; ++b) acc[a][b] = (f32x4)0.f;

  for (int kk = 0; kk < 4; ++kk) {
    const int k0 = kk * 64;
#pragma unroll
    for (int ii = 0; ii < 2; ++ii) {
      int i = wave * 2 + ii;
      int row = i * 4 + rq;
      int k8 = cl ^ (row & 15);
      int grow = m0 + row; if (grow > NV - 1) grow = NV - 1;
      gld16((const char*)x + ((size_t)grow * 256 + k0) * 4 + k8 * 16,
            (char*)xt + i * 1024);
    }
#pragma unroll
    for (int ii = 0; ii < 16; ++ii) {
      int i = wave * 16 + ii;
      int n = i * 8 + (lane >> 3);
      int k8 = (lane & 7) ^ (n & 7);
      gld16((const char*)wtbc + ((size_t)n * 256 + k0) * 2 + k8 * 16,
            (char*)wtb + i * 1024);
    }
    __syncthreads();
#pragma unroll
    for (int ks = 0; ks < 2; ++ks) {
      s16x8 a[2], b[8];
#pragma unroll
      for (int mt = 0; mt < 2; ++mt) {
        int row = mt * 16 + cl;
        int sbase = ks * 8 + rq * 2;
        int sw = (row & 15) << 4;
        f32x4 f0 = *(const f32x4*)((const char*)xt + row * 256 + (((sbase    ) << 4) ^ sw));
        f32x4 f1 = *(const f32x4*)((const char*)xt + row * 256 + (((sbase + 1) << 4) ^ sw));
        s16x8 t;
        t[0] = f2bf(f0[0]); t[1] = f2bf(f0[1]); t[2] = f2bf(f0[2]); t[3] = f2bf(f0[3]);
        t[4] = f2bf(f1[0]); t[5] = f2bf(f1[1]); t[6] = f2bf(f1[2]); t[7] = f2bf(f1[3]);
        a[mt] = t;
      }
#pragma unroll
      for (int nt = 0; nt < 8; ++nt) {
        int n = wave * 128 + nt * 16 + cl;
        int byt = n * 128 + ((((ks * 4 + rq)) << 4) ^ ((n & 7) << 4));
        b[nt] = *(const s16x8*)((const char*)wtb + byt);
      }
#pragma unroll
      for (int mt = 0; mt < 2; ++mt)
#pragma unroll
        for (int nt = 0; nt < 8; ++nt)
          acc[mt][nt] = __builtin_amdgcn_mfma_f32_16x16x32_bf16(a[mt], b[nt], acc[mt][nt], 0, 0, 0);
    }
    __syncthreads();
  }
  float b1v[8];
#pragma unroll
  for (int nt = 0; nt < 8; ++nt) {
    int col = wave * 128 + nt * 16 + cl;
    b1v[nt] = (col >= 256) ? b1[col - 256] : 0.f;
  }
#pragma unroll
  for (int mt = 0; mt < 2; ++mt)
#pragma unroll
    for (int q = 0; q < 4; ++q) {
      int row = m0 + mt * 16 + rq * 4 + q;
      if (row < NV) {
#pragma unroll
        for (int nt = 0; nt < 8; ++nt) {
          int col = wave * 128 + nt * 16 + cl;
          xbc[(size_t)row * 512 + col] = (uint16_t)f2bf(acc[mt][nt][q] + b1v[nt]);
        }
      }
    }
}

// ------------------------------------------------- edge GEMM + epilogue + SUMS
// grid<=256 persistent, 512 thr = 8 waves (2 row-grp x 4 col-grp), grid-stride
// over 64-row tiles. W1a^T RESIDENT in LDS 128 KB: byte = n*512 + ((k8^(n&7))<<4).
// et 32 KB, triple-duty per tile:
//   (1) e-tile chunk-major: byte = c8*1024 + ((r*16)^((c8&3)<<4)) + (col&7)*2
//   (2) acc relayout (same chunk-major addressing)
//   (3) h d-major for sums B-frags: byte = (r>>5)*16384 + d*64
//        + ((rl*2) ^ (((d>>3)&3)<<4)), rl=r&31  -> B-frag = ONE ds_read_b128.
// Sums: per-wave one-hot MFMA (wave owns d in [w*32,w*32+32)); counts = ones-B
// MFMA on wave 0. seg from uniform i32x4 srcI loads + L2-resident batch gathers.
template <bool BF16H>
__global__ __launch_bounds__(512, 1) void k_edgegemm(
    const float* __restrict__ e, const uint16_t* __restrict__ wta,
    const uint16_t* __restrict__ xbc,
    const int* __restrict__ srcI, const int* __restrict__ dstI,
    const int* __restrict__ batch, void* __restrict__ hout,
    int* __restrict__ seg, float* __restrict__ part, int E, int ntiles) {
  __shared__ alignas(16) uint16_t wl[256 * 256];  // 128 KB resident W1a^T
  __shared__ alignas(16) uint16_t et[64 * 256];   // 32 KB multi-purpose
  const int tid = threadIdx.x, wave = tid >> 6, lane = tid & 63;
  const int wr = wave >> 2, wc = wave & 3;
  const int cl = lane & 15, rq = lane >> 4;
  const int rr = tid >> 3;                 // 0..63 (row in tile)
  const int cb = tid & 7;                  // chunk base

  // ---- stage resident W once ----
#pragma unroll
  for (int i = 0; i < 16; ++i) {
    int n = i * 16 + (tid >> 5);
    int k8 = (tid & 31) ^ (n & 7);
    gld16((const char*)wta + ((size_t)n * 256 + k8 * 8) * 2,
          (char*)wl + i * 8192 + tid * 16);
  }

  // sums accumulators: wave owns d in [wave*32, wave*32+32)
  f32x4 accS[4][2], accQ[4][2], accC[4];
#pragma unroll
  for (int gt = 0; gt < 4; ++gt) {
    accC[gt] = (f32x4)0.f;
#pragma unroll
    for (int dt = 0; dt < 2; ++dt) { accS[gt][dt] = (f32x4)0.f; accQ[gt][dt] = (f32x4)0.f; }
  }

  f32x4 er[8];                             // e prefetch: 4 chunks x 2 f32x4
  auto loadE = [&](int t) {
    int r = t * 64 + rr; int rc = r < E ? r : E - 1;
    const float* ep = e + (size_t)rc * 256;
#pragma unroll
    for (int i = 0; i < 4; ++i) {
      int s = cb + 8 * i;
      er[2 * i]     = *(const f32x4*)(ep + s * 8);
      er[2 * i + 1] = *(const f32x4*)(ep + s * 8 + 4);
    }
  };
  auto writeE = [&]() {
#pragma unroll
    for (int i = 0; i < 4; ++i) {
      int s = cb + 8 * i;
      f32x4 f0 = er[2 * i], f1 = er[2 * i + 1];
      s16x8 t;
      t[0] = f2bf(f0[0]); t[1] = f2bf(f0[1]); t[2] = f2bf(f0[2]); t[3] = f2bf(f0[3]);
      t[4] = f2bf(f1[0]); t[5] = f2bf(f1[1]); t[6] = f2bf(f1[2]); t[7] = f2bf(f1[3]);
      *(s16x8*)((char*)et + s * 1024 + ((rr * 16) ^ ((s & 3) << 4))) = t;
    }
  };

  int t = blockIdx.x;
  const int G = gridDim.x;
  if (t < ntiles) { loadE(t); writeE(); }
  __syncthreads();                          // W staged + e(tile0) visible

  for (; t < ntiles; t += G) {
    const int tn = t + G;
    const int rt = t * 64;
    // idx for current tile (per-thread row rr)
    int r = rt + rr;
    bool valid = r < E;
    int rc = valid ? r : E - 1;
    int sA = srcI[rc], dA = dstI[rc];
    int gseg = batch[sA];
    if (tn < ntiles) loadE(tn);             // prefetch next e (hidden under K-loop)

    // ---- barrier-free K-loop over resident W ----
    f32x4 acc[2][4];
#pragma unroll
    for (int a = 0; a < 2; ++a)
#pragma unroll
      for (int b = 0; b < 4; ++b) acc[a][b] = (f32x4)0.f;
#pragma unroll
    for (int kk = 0; kk < 8; ++kk) {
      s16x8 a[2], b[4];
#pragma unroll
      for (int mt = 0; mt < 2; ++mt) {
        int row = wr * 32 + mt * 16 + cl;
        int c8s = kk * 4 + rq;
        a[mt] = *(const s16x8*)((const char*)et + c8s * 1024 + ((row * 16) ^ (rq << 4)));
      }
#pragma unroll
      for (int nt = 0; nt < 4; ++nt) {
        int n = wc * 64 + nt * 16 + cl;
        int kc = kk * 4 + rq;
        b[nt] = *(const s16x8*)((const char*)wl + n * 512 + ((kc ^ (n & 7)) << 4));
      }
#pragma unroll
      for (int mt = 0; mt < 2; ++mt)
#pragma unroll
        for (int nt = 0; nt < 4; ++nt)
          acc[mt][nt] = __builtin_amdgcn_mfma_f32_16x16x32_bf16(a[mt], b[nt], acc[mt][nt], 0, 0, 0);
    }

    // ---- gathers for current tile ----
    u32x4 gb[4], gc[4];
#pragma unroll
    for (int i = 0; i < 4; ++i) {
      int c8 = cb + 8 * i;
      gb[i] = *(const u32x4*)(xbc + (size_t)sA * 512 + c8 * 8);
      gc[i] = *(const u32x4*)(xbc + (size_t)dA * 512 + 256 + c8 * 8);
    }
    // ---- seg values for sums A-frags: lane (cl,rq) needs rows ks*32+rq*8+j.
    //      Full tile: uniform i32x4 srcI loads (16 lanes same addr -> broadcast)
    //      + 8 batch gathers (40KB L2-resident). Tail tile: clamped scalar.
    int gsg[16];
    if (part) {
      if (rt + 64 <= E) {
#pragma unroll
        for (int ks = 0; ks < 2; ++ks) {
          const int* sp = srcI + rt + ks * 32 + rq * 8;
          i32x4 v0 = *(const i32x4*)sp;
          i32x4 v1 = *(const i32x4*)(sp + 4);
#pragma unroll
          for (int j = 0; j < 4; ++j) {
            gsg[ks * 8 + j]     = batch[v0[j]];
            gsg[ks * 8 + 4 + j] = batch[v1[j]];
          }
        }
      } else {
#pragma unroll
        for (int k2 = 0; k2 < 16; ++k2) {
          int rs = rt + (k2 >> 3) * 32 + rq * 8 + (k2 & 7);
          gsg[k2] = (rs < E) ? batch[srcI[rs]] : -1;
        }
      }
    }
    // ---- e residual out of et before relayout clobbers it ----
    s16x8 ev[4];
#pragma unroll
    for (int i = 0; i < 4; ++i) {
      int c8 = cb + 8 * i;
      ev[i] = *(const s16x8*)((const char*)et + c8 * 1024 + ((rr * 16) ^ ((c8 & 3) << 4)));
    }
    __syncthreads();                        // A: all e-reads of et done

    // ---- relayout acc -> et (bf16, chunk-major) ----
#pragma unroll
    for (int mt = 0; mt < 2; ++mt)
#pragma unroll
      for (int nt = 0; nt < 4; ++nt) {
        int col = wc * 64 + nt * 16 + cl;
        int c8 = col >> 3;
        char* base = (char*)et + c8 * 1024 + (col & 7) * 2;
#pragma unroll
        for (int q = 0; q < 4; ++q) {
          int row = wr * 32 + mt * 16 + rq * 4 + q;
          *(uint16_t*)(base + ((row * 16) ^ ((c8 & 3) << 4))) =
              (uint16_t)f2bf(acc[mt][nt][q]);
        }
      }
    __syncthreads();                        // B: relayout visible

    // ---- combine + store h; keep bf16 h in regs for the d-major transpose ----
    if (cb == 0 && valid) seg[r] = gseg;
    s16x8 hov[4];
#pragma unroll
    for (int i = 0; i < 4; ++i) {
      int c8 = cb + 8 * i;
      int sw = (c8 & 3) << 4;
      s16x8 av = *(const s16x8*)((const char*)et + c8 * 1024 + ((rr * 16) ^ sw));
      f32x4 f0, f1;
#pragma unroll
      for (int j = 0; j < 8; ++j) {
        uint32_t xbw = ((const uint32_t*)&gb[i])[j >> 1];
        uint32_t xcw = ((const uint32_t*)&gc[i])[j >> 1];
        float xbf = bf2f((j & 1) ? (xbw >> 16) : xbw);
        float xcf = bf2f((j & 1) ? (xcw >> 16) : xcw);
        float de = bf2f((uint16_t)av[j]) + xbf + xcf;      // b1 folded in xc
        float sig = 1.f / (1.f + __expf(-de));
        float h = bf2f((uint16_t)ev[i][j]) + de * sig;
        hov[i][j] = f2bf(h);
        if (!BF16H) { if (j < 4) f0[j] = h; else f1[j - 4] = h; }
      }
      if (valid) {
        if (BF16H) {
          *(s16x8*)((uint16_t*)hout + (size_t)r * 256 + c8 * 8) = hov[i];
        } else {
          float* hp_ = (float*)hout + (size_t)r * 256 + c8 * 8;
          *(f32x4*)hp_ = f0; *(f32x4*)(hp_ + 4) = f1;
        }
      }
    }
    __syncthreads();                        // C: et combine-reads done

    // ---- h -> et d-major (swz granule = (d>>3)&3 = c8&3, const per chunk) ----
    if (part) {
      const int H16 = (rr >> 5) * 16384;
      const int rl2 = (rr & 31) * 2;
#pragma unroll
      for (int i = 0; i < 4; ++i) {
        int c8 = cb + 8 * i;
        char* base = (char*)et + H16 + c8 * 512 + (rl2 ^ ((c8 & 3) << 4));
#pragma unroll
        for (int j = 0; j < 8; ++j)
          *(uint16_t*)(base + j * 64) = (uint16_t)hov[i][j];   // invalid rows: one-hot=0
      }
    }
    __syncthreads();                        // D: d-major visible

    // ---- sums: per-wave one-hot MFMA over the 64 rows ----
    if (part) {
#pragma unroll
      for (int ks = 0; ks < 2; ++ks) {
        s16x8 afk[4];
#pragma unroll
        for (int gt = 0; gt < 4; ++gt) {
          int gcol = gt * 16 + cl;
          u32x4 aw;
#pragma unroll
          for (int jp = 0; jp < 4; ++jp)
            aw[jp] = (gsg[ks * 8 + 2 * jp]     == gcol ? 0x3F80u     : 0u)
                   | (gsg[ks * 8 + 2 * jp + 1] == gcol ? 0x3F800000u : 0u);
          afk[gt] = __builtin_bit_cast(s16x8, aw);
        }
#pragma unroll
        for (int dt = 0; dt < 2; ++dt) {
          int d = wave * 32 + dt * 16 + cl;
          s16x8 bf = *(const s16x8*)((const char*)et + ks * 16384 + d * 64
                                     + ((rq * 16) ^ (((d >> 3) & 3) << 4)));
          s16x8 qf;
#pragma unroll
          for (int j = 0; j < 8; ++j) {
            float f = bf2f((uint16_t)bf[j]);
            qf[j] = f2bf(f * f);
          }
#pragma unroll
          for (int gt = 0; gt < 4; ++gt) {
            accS[gt][dt] = __builtin_amdgcn_mfma_f32_16x16x32_bf16(afk[gt], bf, accS[gt][dt], 0, 0, 0);
            accQ[gt][dt] = __builtin_amdgcn_mfma_f32_16x16x32_bf16(afk[gt], qf, accQ[gt][dt], 0, 0, 0);
          }
        }
        if (wave == 0) {                    // counts: B = ones
          s16x8 ones;
#pragma unroll
          for (int j = 0; j < 8; ++j) ones[j] = (short)0x3F80;
#pragma unroll
          for (int gt = 0; gt < 4; ++gt)
            accC[gt] = __builtin_amdgcn_mfma_f32_16x16x32_bf16(afk[gt], ones, accC[gt], 0, 0, 0);
        }
      }
    }
    __syncthreads();                        // E: et sums-reads done

    if (tn < ntiles) writeE();              // stage e for next tile
    __syncthreads();                        // F: next e visible
  }

  // ---- write per-block sum partials ----
  if (part) {
    float* pb = part + (size_t)blockIdx.x * PSTRIDE;
#pragma unroll
    for (int gt = 0; gt < 4; ++gt)
#pragma unroll
      for (int dt = 0; dt < 2; ++dt)
#pragma unroll
        for (int q = 0; q < 4; ++q) {
          int g = gt * 16 + rq * 4 + q;     // C-frag: row=(lane>>4)*4+reg
          int d = wave * 32 + dt * 16 + cl; //         col=lane&15
          pb[g * 256 + d] = accS[gt][dt][q];
          pb[NGRAPH * 256 + g * 256 + d] = accQ[gt][dt][q];
        }
    if (wave == 0 && cl == 0) {
#pragma unroll
      for (int gt = 0; gt < 4; ++gt)
#pragma unroll
        for (int q = 0; q < 4; ++q)
          pb[NGRAPH * 256 * 2 + gt * 16 + rq * 4 + q] = accC[gt][q];
    }
  }
}

// ------------------------------------------------- legacy atomic k_sums (fallback)
__global__ __launch_bounds__(512, 1) void k_sums_atomic(const float* __restrict__ h,
                                                        const int* __restrict__ seg,
                                                        float* __restrict__ gsum,
                                                        float* __restrict__ gsq,
                                                        float* __restrict__ gcnt, int E) {
  __shared__ float ls[NGRAPH * 256];      // d-permuted layout
  __shared__ float lq[NGRAPH * 256];
  __shared__ float lc[NGRAPH];
  const int t = threadIdx.x;
  for (int i = t; i < NGRAPH * 256; i += 512) { ls[i] = 0.f; lq[i] = 0.f; }
  if (t < NGRAPH) lc[t] = 0.f;
  __syncthreads();
  const int ro = t >> 5, c = t & 31;
  const int step = gridDim.x * 16;
  for (int r0 = blockIdx.x * 16; r0 < E; r0 += step) {
    int r = r0 + ro;
    if (r < E) {
      int g = seg[r];
      const float* hp = h + (size_t)r * 256 + c * 8;
      if (c == 0) ds_addf(&lc[g], 1.f);
      float* bs = ls + g * 256;
      float* bq = lq + g * 256;
#pragma unroll
      for (int j = 0; j < 8; ++j) {
        int dp = c | (j << 5);
        float v = hp[j];
        ds_addf(&bs[dp], v);
        ds_addf(&bq[dp], v * v);
      }
    }
  }
  asm volatile("s_waitcnt lgkmcnt(0)" ::: "memory");
  __syncthreads();
  for (int i = t; i < NGRAPH * 256; i += 512) {
    unsafeAtomicAdd(&gsum[i], ls[i]);
    unsafeAtomicAdd(&gsq[i], lq[i]);
  }
  if (t < NGRAPH) unsafeAtomicAdd(&gcnt[t], lc[t]);
}

// ------------------------------------------------- per-(g,d) affine tables
// NB>0: reduce NB block-partials (natural layout); NB==0: legacy dperm'd tables
__global__ __launch_bounds__(256) void k_stats(const float* __restrict__ part, int NB,
                                               const float* __restrict__ gsum,
                                               const float* __restrict__ gsq,
                                               const float* __restrict__ gcnt,
                                               const float* __restrict__ w,
                                               const float* __restrict__ b,
                                               const float* __restrict__ ms,
                                               float* __restrict__ atab,
                                               float* __restrict__ ctab) {
  int g = blockIdx.x, d = threadIdx.x;
  float s = 0.f, q = 0.f, cn = 0.f;
  if (NB > 0) {
    const float* ps = part + g * 256 + d;
    const float* pq = part + NGRAPH * 256 + g * 256 + d;
    const float* pc = part + NGRAPH * 256 * 2 + g;
#pragma unroll 4
    for (int bb = 0; bb < NB; ++bb) {
      size_t o = (size_t)bb * PSTRIDE;
      s  += ps[o];
      q  += pq[o];
      cn += pc[o];
    }
  } else {
    int dp = dperm(d);
    s = gsum[g * 256 + dp]; q = gsq[g * 256 + dp]; cn = gcnt[g];
  }
  float cnt = fmaxf(cn, 1.f);
  float m   = s / cnt;
  float msq = q / cnt;
  float sc  = ms[d];
  float var = msq - m * m * sc * (2.f - sc);
  float rstd = rsqrtf(fmaxf(var, 0.f) + 1e-5f);
  float A = w[d] * rstd;
  atab[g * 256 + d] = A;
  ctab[g * 256 + d] = b[d] - A * sc * m;
}

// ------------------------------------------------- apply: out = A[g]*h + C[g]
template <bool BF16H>
__global__ __launch_bounds__(256) void k_apply(const void* __restrict__ h,
                                               const int* __restrict__ seg,
                                               const float* __restrict__ atab,
                                               const float* __restrict__ ctab,
                                               float* __restrict__ out, int E) {
  const long long total = (long long)E * 32;
  for (long long i = (long long)blockIdx.x * 256 + threadIdx.x; i < total;
       i += (long long)gridDim.x * 256) {
    int row = (int)(i >> 5);
    int c8 = ((int)i & 31) * 8;
    int g = seg[row];
    const f32x4* Ap = (const f32x4*)(atab + g * 256 + c8);
    const f32x4* Cp = (const f32x4*)(ctab + g * 256 + c8);
    f32x4 A0 = Ap[0], A1 = Ap[1], C0 = Cp[0], C1 = Cp[1];
    f32x4 h0, h1;
    if (BF16H) {
      u32x4 p = *(const u32x4*)((const uint16_t*)h + (size_t)row * 256 + c8);
      h0[0] = bf2f(p[0]); h0[1] = bf2f(p[0] >> 16);
      h0[2] = bf2f(p[1]); h0[3] = bf2f(p[1] >> 16);
      h1[0] = bf2f(p[2]); h1[1] = bf2f(p[2] >> 16);
      h1[2] = bf2f(p[3]); h1[3] = bf2f(p[3] >> 16);
    } else {
      const f32x4* hp = (const f32x4*)((const float*)h + (size_t)row * 256 + c8);
      h0 = hp[0]; h1 = hp[1];
    }
    f32x4 o0 = A0 * h0 + C0, o1 = A1 * h1 + C1;
    f32x4* op = (f32x4*)(out + (size_t)row * 256 + c8);
    op[0] = o0; op[1] = o1;
  }
}

// ----------------------------------------------------------------- launch
extern "C" void kernel_launch(void* const* d_in, const int* in_sizes, int n_in,
                              void* d_out, int out_size, void* d_ws, size_t ws_size,
                              hipStream_t stream) {
  const float* x     = (const float*)d_in[0];
  const float* e     = (const float*)d_in[1];
  const int*   batch = (const int*)d_in[2];
  const int*   eidx  = (const int*)d_in[3];
  const float* W1    = (const float*)d_in[4];
  const float* b1    = (const float*)d_in[5];
  const float* gw    = (const float*)d_in[6];
  const float* gb    = (const float*)d_in[7];
  const float* gms   = (const float*)d_in[8];
  const int NV = in_sizes[0] / 256;
  const int E  = in_sizes[1] / 256;
  const int* srcI = eidx;
  const int* dstI = eidx + E;

  char* ws = (char*)d_ws;
  size_t off = 0;
  auto alloc = [&](size_t bytes) {
    size_t o = off;
    off += (bytes + 255) & ~(size_t)255;
    return o;
  };
  size_t o_wta  = alloc(256 * 256 * 2);
  size_t o_wtbc = alloc(512 * 256 * 2);
  size_t o_gsum = alloc(NGRAPH * 256 * 4);
  size_t o_gsq  = alloc(NGRAPH * 256 * 4);
  size_t o_gcnt = alloc(256);
  size_t o_atab = alloc(NGRAPH * 256 * 4);
  size_t o_ctab = alloc(NGRAPH * 256 * 4);
  size_t o_seg  = alloc((size_t)E * 4);
  size_t o_xbc  = alloc((size_t)NV * 512 * 2);     // bf16
  size_t o_h    = alloc((size_t)E * 256 * 2);
  const bool fast = ws_size >= off;   // h (bf16) fits in ws? else stage f32 in d_out

  uint16_t* wta  = (uint16_t*)(ws + o_wta);
  uint16_t* wtbc = (uint16_t*)(ws + o_wtbc);
  float* gsum = (float*)(ws + o_gsum);
  float* gsq  = (float*)(ws + o_gsq);
  float* gcnt = (float*)(ws + o_gcnt);
  float* atab = (float*)(ws + o_atab);
  float* ctab = (float*)(ws + o_ctab);
  int*   seg  = (int*)(ws + o_seg);
  uint16_t* xbc = (uint16_t*)(ws + o_xbc);
  void*  hbuf = fast ? (void*)(ws + o_h) : d_out;
  // fast path: block-partials at the START of d_out (<33 MB << 164 MB);
  // written by fused edgegemm, consumed by k_stats, then overwritten by k_apply.
  float* part = fast ? (float*)d_out : nullptr;

  const int ntiles = (E + 63) / 64;
  const int egrid = ntiles < 256 ? ntiles : 256;
  const int NB = fast ? egrid : 0;

  k_wconv<<<768, 256, 0, stream>>>(W1, wta, wtbc);
  k_nodegemm<<<(NV + 31) / 32, 256, 0, stream>>>(x, wtbc, b1, xbc, NV);
  if (fast) {
    k_edgegemm<true><<<egrid, 512, 0, stream>>>(e, wta, xbc, srcI, dstI,
                                                batch, hbuf, seg, part, E, ntiles);
  } else {
    const int nz = NGRAPH * 256 * 2 + 64;   // gsum|gsq|gcnt contiguous
    k_zero<<<(nz + 255) / 256, 256, 0, stream>>>(gsum, nz);
    k_edgegemm<false><<<egrid, 512, 0, stream>>>(e, wta, xbc, srcI, dstI,
                                                 batch, hbuf, seg, nullptr, E, ntiles);
    k_sums_atomic<<<256, 512, 0, stream>>>((const float*)hbuf, seg, gsum, gsq, gcnt, E);
  }
  k_stats<<<NGRAPH, 256, 0, stream>>>(part, NB, gsum, gsq, gcnt, gw, gb, gms, atab, ctab);
  if (fast)
    k_apply<true><<<2048, 256, 0, stream>>>(hbuf, seg, atab, ctab, (float*)d_out, E);
  else
    k_apply<false><<<2048, 256, 0, stream>>>(hbuf, seg, atab, ctab, (float*)d_out, E);
}